// Round 1
// baseline (996.027 us; speedup 1.0000x reference)
//
#include <hip/hip_runtime.h>
#include <hip/hip_bf16.h>
#include <cmath>

using short8 = __attribute__((ext_vector_type(8))) short;
using f32x4  = __attribute__((ext_vector_type(4))) float;

#define MFMA16 __builtin_amdgcn_mfma_f32_16x16x32_bf16

__device__ __forceinline__ unsigned short f2bf(float f) {
    union { float f; unsigned u; } v; v.f = f;
    unsigned u = v.u;
    return (unsigned short)((u + 0x7FFFu + ((u >> 16) & 1u)) >> 16);  // RNE
}
__device__ __forceinline__ float bf2f(unsigned short h) {
    union { unsigned u; float f; } v; v.u = ((unsigned)h) << 16;
    return v.f;
}
__device__ __forceinline__ float softplus(float x) {
    return fmaxf(x, 0.f) + log1pf(expf(-fabsf(x)));  // stable
}

// ---------------- weight packing: B-fragment order, bf16, zero-padded ----------------
// packed[((ct*KT + kk)*64 + lane)*8 + j] = W[k][m], m = ct*16 + (lane&15),
//                                          k = kk*32 + (lane>>4)*8 + j
__global__ void pack_w(const float* __restrict__ W, unsigned short* __restrict__ out,
                       int K_real, int M_real, int KT, int CT) {
    int tid = blockIdx.x * blockDim.x + threadIdx.x;
    int total = CT * KT * 64;
    if (tid >= total) return;
    int lane = tid & 63;
    int t    = tid >> 6;
    int kk   = t % KT;
    int ct   = t / KT;
    int m  = ct * 16 + (lane & 15);
    int k0 = kk * 32 + ((lane >> 4) << 3);
    short8 v;
#pragma unroll
    for (int j = 0; j < 8; ++j) {
        int k = k0 + j;
        float f = (k < K_real && m < M_real) ? W[(size_t)k * M_real + m] : 0.f;
        v[j] = (short)f2bf(f);
    }
    *(((short8*)out) + tid) = v;
}

// ---------------- fused MLP + loss partials ----------------
// 32 rows per block, 8 waves. LDS (ushort units):
//   h1 [32][1024] at 0      (64 KB, rowBytes 2048, XOR-swizzled)
//   h2 [32][512]  at 32768  (32 KB, rowBytes 1024)
//   h3 [32][256]  at 49152  (16 KB, rowBytes  512)
__global__ __launch_bounds__(512, 2) void fused_mlp(
    const float* __restrict__ Xf, const float* __restrict__ Xr,
    const unsigned short* __restrict__ pW1, const unsigned short* __restrict__ pW2,
    const unsigned short* __restrict__ pW3,
    const float* __restrict__ b1, const float* __restrict__ b2,
    const float* __restrict__ b3, const float* __restrict__ W4,
    const float* __restrict__ b4, float* __restrict__ partials)
{
    __shared__ unsigned short sh[57344];
    __shared__ float red[64];

    const int tidx = threadIdx.x;
    const int wid  = tidx >> 6;
    const int lane = tidx & 63;
    const int l15  = lane & 15;
    const int lgrp = lane >> 4;

    const long grow0 = (long)blockIdx.x * 32;   // blocks 0..2047 fake, 2048..4095 real
    const float* X = (grow0 < 65536) ? (Xf + (size_t)grow0 * 512)
                                     : (Xr + (size_t)(grow0 - 65536) * 512);

    // ================= Layer 1: X[32x512] @ W1 -> h1[32x1024] =================
    // A-fragments for all 32 rows, K=512 (16 ksteps), held in registers.
    short8 a1[2][16];
#pragma unroll
    for (int rt = 0; rt < 2; ++rt) {
        const float* rp = X + (size_t)(rt * 16 + l15) * 512 + lgrp * 8;
#pragma unroll
        for (int kk = 0; kk < 16; ++kk) {
            const float4* q = (const float4*)(rp + kk * 32);
            float4 f0 = q[0], f1 = q[1];
            short8 a;
            a[0] = (short)f2bf(f0.x); a[1] = (short)f2bf(f0.y);
            a[2] = (short)f2bf(f0.z); a[3] = (short)f2bf(f0.w);
            a[4] = (short)f2bf(f1.x); a[5] = (short)f2bf(f1.y);
            a[6] = (short)f2bf(f1.z); a[7] = (short)f2bf(f1.w);
            a1[rt][kk] = a;
        }
    }

    for (int c = 0; c < 8; ++c) {          // 8 col-tiles per wave (64 total)
        int ct = wid * 8 + c;
        const short8* bp = (const short8*)pW1 + (size_t)(ct * 16) * 64 + lane;
        f32x4 acc0 = {0.f, 0.f, 0.f, 0.f}, acc1 = {0.f, 0.f, 0.f, 0.f};
#pragma unroll
        for (int kk = 0; kk < 16; ++kk) {
            short8 b = bp[kk * 64];
            acc0 = MFMA16(a1[0][kk], b, acc0, 0, 0, 0);
            acc1 = MFMA16(a1[1][kk], b, acc1, 0, 0, 0);
        }
        int col = ct * 16 + l15;
        float bias = (col < 1000) ? b1[col] : 0.f;
#pragma unroll
        for (int i = 0; i < 4; ++i) {
            int r0 = lgrp * 4 + i;
            int r1 = r0 + 16;
            float v0 = fmaxf(acc0[i] + bias, 0.f);
            float v1 = fmaxf(acc1[i] + bias, 0.f);
            sh[(r0 * 2048 + ((col * 2) ^ ((r0 & 7) << 4))) >> 1] = f2bf(v0);
            sh[(r1 * 2048 + ((col * 2) ^ ((r1 & 7) << 4))) >> 1] = f2bf(v1);
        }
    }
    __syncthreads();

    // ================= Layer 2: h1[32x1024] @ W2 -> h2[32x512] =================
    f32x4 acc2[4][2];
#pragma unroll
    for (int c = 0; c < 4; ++c) {
        acc2[c][0] = f32x4{0.f, 0.f, 0.f, 0.f};
        acc2[c][1] = f32x4{0.f, 0.f, 0.f, 0.f};
    }
    for (int kc = 0; kc < 4; ++kc) {       // 4 chunks x 8 ksteps = K 1024
        short8 a2[2][8];
#pragma unroll
        for (int rt = 0; rt < 2; ++rt) {
            int row = rt * 16 + l15;
#pragma unroll
            for (int k8 = 0; k8 < 8; ++k8) {
                int k0 = (kc * 8 + k8) * 32 + lgrp * 8;
                a2[rt][k8] = *(const short8*)&sh[(row * 2048 + ((k0 * 2) ^ ((row & 7) << 4))) >> 1];
            }
        }
#pragma unroll
        for (int c = 0; c < 4; ++c) {
            int ct = wid * 4 + c;
            const short8* bp = (const short8*)pW2 + (size_t)(ct * 32 + kc * 8) * 64 + lane;
#pragma unroll
            for (int k8 = 0; k8 < 8; ++k8) {
                short8 b = bp[k8 * 64];
                acc2[c][0] = MFMA16(a2[0][k8], b, acc2[c][0], 0, 0, 0);
                acc2[c][1] = MFMA16(a2[1][k8], b, acc2[c][1], 0, 0, 0);
            }
        }
    }
#pragma unroll
    for (int c = 0; c < 4; ++c) {
        int ct = wid * 4 + c;
        int col = ct * 16 + l15;
        float bias = (col < 500) ? b2[col] : 0.f;
#pragma unroll
        for (int i = 0; i < 4; ++i) {
            int r0 = lgrp * 4 + i;
            int r1 = r0 + 16;
            float v0 = fmaxf(acc2[c][0][i] + bias, 0.f);
            float v1 = fmaxf(acc2[c][1][i] + bias, 0.f);
            sh[32768 + ((r0 * 1024 + ((col * 2) ^ ((r0 & 7) << 4))) >> 1)] = f2bf(v0);
            sh[32768 + ((r1 * 1024 + ((col * 2) ^ ((r1 & 7) << 4))) >> 1)] = f2bf(v1);
        }
    }
    __syncthreads();

    // ================= Layer 3: h2[32x512] @ W3 -> h3[32x256] =================
    f32x4 acc3[2][2];
#pragma unroll
    for (int c = 0; c < 2; ++c) {
        acc3[c][0] = f32x4{0.f, 0.f, 0.f, 0.f};
        acc3[c][1] = f32x4{0.f, 0.f, 0.f, 0.f};
    }
    for (int kc = 0; kc < 2; ++kc) {       // 2 chunks x 8 ksteps = K 512
        short8 a3[2][8];
#pragma unroll
        for (int rt = 0; rt < 2; ++rt) {
            int row = rt * 16 + l15;
#pragma unroll
            for (int k8 = 0; k8 < 8; ++k8) {
                int k0 = (kc * 8 + k8) * 32 + lgrp * 8;
                a3[rt][k8] = *(const short8*)&sh[32768 + ((row * 1024 + ((k0 * 2) ^ ((row & 7) << 4))) >> 1)];
            }
        }
#pragma unroll
        for (int c = 0; c < 2; ++c) {
            int ct = wid * 2 + c;
            const short8* bp = (const short8*)pW3 + (size_t)(ct * 16 + kc * 8) * 64 + lane;
#pragma unroll
            for (int k8 = 0; k8 < 8; ++k8) {
                short8 b = bp[k8 * 64];
                acc3[c][0] = MFMA16(a3[0][k8], b, acc3[c][0], 0, 0, 0);
                acc3[c][1] = MFMA16(a3[1][k8], b, acc3[c][1], 0, 0, 0);
            }
        }
    }
#pragma unroll
    for (int c = 0; c < 2; ++c) {
        int ct = wid * 2 + c;
        int col = ct * 16 + l15;
        float bias = (col < 250) ? b3[col] : 0.f;
#pragma unroll
        for (int i = 0; i < 4; ++i) {
            int r0 = lgrp * 4 + i;
            int r1 = r0 + 16;
            float v0 = fmaxf(acc3[c][0][i] + bias, 0.f);
            float v1 = fmaxf(acc3[c][1][i] + bias, 0.f);
            sh[49152 + ((r0 * 512 + ((col * 2) ^ ((r0 & 7) << 4))) >> 1)] = f2bf(v0);
            sh[49152 + ((r1 * 512 + ((col * 2) ^ ((r1 & 7) << 4))) >> 1)] = f2bf(v1);
        }
    }
    __syncthreads();

    // ================= Layer 4 + loss: z = h3 . W4 + b4 =================
    {
        int g   = tidx >> 4;     // row 0..31
        int t16 = tidx & 15;
        int colb = t16 * 16;
        float sum = 0.f;
        short8 v0 = *(const short8*)&sh[49152 + ((g * 512 + ((colb * 2)      ^ ((g & 7) << 4))) >> 1)];
        short8 v1 = *(const short8*)&sh[49152 + ((g * 512 + ((colb * 2 + 16) ^ ((g & 7) << 4))) >> 1)];
#pragma unroll
        for (int j = 0; j < 8; ++j) {
            int c0 = colb + j, c1 = colb + 8 + j;
            if (c0 < 250) sum += bf2f((unsigned short)v0[j]) * W4[c0];
            if (c1 < 250) sum += bf2f((unsigned short)v1[j]) * W4[c1];
        }
#pragma unroll
        for (int off = 8; off > 0; off >>= 1) sum += __shfl_down(sum, off, 16);
        if (t16 == 0) {
            float z = sum + b4[0];
            bool fake = (grow0 < 65536);
            float spn = softplus(-z);
            red[g]      = fake ? spn : 0.f;               // loss_F part
            red[32 + g] = fake ? softplus(z) : spn;       // loss_D part
        }
    }
    __syncthreads();
    if (tidx == 0) {
        float pF = 0.f, pD = 0.f;
        for (int i = 0; i < 32; ++i) { pF += red[i]; pD += red[32 + i]; }
        partials[(size_t)blockIdx.x * 2]     = pF;
        partials[(size_t)blockIdx.x * 2 + 1] = pD;
    }
}

// ---------------- final reduction ----------------
__global__ void reduce_partials(const float* __restrict__ partials, int nblocks,
                                float* __restrict__ out) {
    __shared__ float sF[256], sD[256];
    float f = 0.f, d = 0.f;
    for (int i = threadIdx.x; i < nblocks; i += 256) {
        f += partials[2 * i];
        d += partials[2 * i + 1];
    }
    sF[threadIdx.x] = f; sD[threadIdx.x] = d;
    __syncthreads();
    for (int s = 128; s > 0; s >>= 1) {
        if (threadIdx.x < s) {
            sF[threadIdx.x] += sF[threadIdx.x + s];
            sD[threadIdx.x] += sD[threadIdx.x + s];
        }
        __syncthreads();
    }
    if (threadIdx.x == 0) { out[0] = sF[0]; out[1] = sD[0]; }
}

extern "C" void kernel_launch(void* const* d_in, const int* in_sizes, int n_in,
                              void* d_out, int out_size, void* d_ws, size_t ws_size,
                              hipStream_t stream) {
    const float* Xf = (const float*)d_in[0];   // repr_xy_hat [65536,512]
    const float* Xr = (const float*)d_in[1];   // repr_xy     [65536,512]
    const float* W1 = (const float*)d_in[2];   // [512,1000]
    const float* b1 = (const float*)d_in[3];
    const float* W2 = (const float*)d_in[4];   // [1000,500]
    const float* b2 = (const float*)d_in[5];
    const float* W3 = (const float*)d_in[6];   // [500,250]
    const float* b3 = (const float*)d_in[7];
    const float* W4 = (const float*)d_in[8];   // [250,1]
    const float* b4 = (const float*)d_in[9];

    // ws layout (elements are ushort for packs):
    unsigned short* pW1 = (unsigned short*)d_ws;          // 64ct*16kk*512 = 524288 (1 MB)
    unsigned short* pW2 = pW1 + 524288;                   // 32ct*32kk*512 = 524288 (1 MB)
    unsigned short* pW3 = pW2 + 524288;                   // 16ct*16kk*512 = 131072 (256 KB)
    float* partials = (float*)(pW3 + 131072);             // 4096*2 floats (32 KB)

    pack_w<<<(64 * 16 * 64 + 255) / 256, 256, 0, stream>>>(W1, pW1, 512, 1000, 16, 64);
    pack_w<<<(32 * 32 * 64 + 255) / 256, 256, 0, stream>>>(W2, pW2, 1000, 500, 32, 32);
    pack_w<<<(16 * 16 * 64 + 255) / 256, 256, 0, stream>>>(W3, pW3, 500, 250, 16, 16);

    fused_mlp<<<4096, 512, 0, stream>>>(Xf, Xr, pW1, pW2, pW3,
                                        b1, b2, b3, W4, b4, partials);

    reduce_partials<<<1, 256, 0, stream>>>(partials, 4096, (float*)d_out);
}

// Round 2
// 484.336 us; speedup vs baseline: 2.0565x; 2.0565x over previous
//
#include <hip/hip_runtime.h>
#include <hip/hip_bf16.h>
#include <cmath>

using short8  = __attribute__((ext_vector_type(8))) short;
using short4v = __attribute__((ext_vector_type(4))) short;
using f32x16  = __attribute__((ext_vector_type(16))) float;

#define MFMA32 __builtin_amdgcn_mfma_f32_32x32x16_bf16

__device__ __forceinline__ unsigned short f2bf(float f) {
    union { float f; unsigned u; } v; v.f = f;
    unsigned u = v.u;
    return (unsigned short)((u + 0x7FFFu + ((u >> 16) & 1u)) >> 16);  // RNE
}
__device__ __forceinline__ float bf2f(unsigned short h) {
    union { unsigned u; float f; } v; v.u = ((unsigned)h) << 16;
    return v.f;
}
__device__ __forceinline__ float softplus(float x) {
    return fmaxf(x, 0.f) + log1pf(expf(-fabsf(x)));  // stable
}

// ---------- weight packing for 32x32x16 MFMA B-fragments, bf16, zero-padded ----------
// out[((ct*KT + kk)*64 + lane)*8 + j] = W[k][m], m = ct*32 + (lane&31),
//                                       k = kk*16 + (lane>>5)*8 + j
__global__ void pack_w32(const float* __restrict__ W, unsigned short* __restrict__ out,
                         int K_real, int M_real, int KT, int CT) {
    int tid = blockIdx.x * blockDim.x + threadIdx.x;
    int total = CT * KT * 64;
    if (tid >= total) return;
    int lane = tid & 63;
    int t    = tid >> 6;
    int kk   = t % KT;
    int ct   = t / KT;
    int m  = ct * 32 + (lane & 31);
    int k0 = kk * 16 + ((lane >> 5) << 3);
    short8 v;
#pragma unroll
    for (int j = 0; j < 8; ++j) {
        int k = k0 + j;
        float f = (k < K_real && m < M_real) ? W[(size_t)k * M_real + m] : 0.f;
        v[j] = (short)f2bf(f);
    }
    *(((short8*)out) + tid) = v;
}

// ---------------- fused MLP + loss partials ----------------
// BM=64 rows/block, 8 waves. 32x32x16 MFMA. LDS byte layout:
//   X region : [0, 16384)        64 rows x 128 bf16 (K-chunk), rowBytes 256, swizzled
//   H region : [16384, 147456)   h1 [64][1024] bf16 (rowBytes 2048)
//                                then h2 [64][512] (rowBytes 1024) overwrites h1[:, :512]
//                                then h3 [64][256] (rowBytes 512) at H+65536
// swizzle: byte_in_row ^= (row & 15) << 4   (bijective; 16 slots -> 2-way max on b128)
__global__ __launch_bounds__(512, 2) void fused_mlp(
    const float* __restrict__ Xf, const float* __restrict__ Xr,
    const unsigned short* __restrict__ pW1, const unsigned short* __restrict__ pW2,
    const unsigned short* __restrict__ pW3,
    const float* __restrict__ b1, const float* __restrict__ b2,
    const float* __restrict__ b3, const float* __restrict__ W4,
    const float* __restrict__ b4, float* __restrict__ partials)
{
    __shared__ __align__(16) unsigned char smem[147456];
    __shared__ float red[128];
    unsigned char* H = smem + 16384;

    const int tidx = threadIdx.x;
    const int wid  = tidx >> 6;
    const int lane = tidx & 63;
    const int l31  = lane & 31;
    const int hi   = lane >> 5;

    const long grow0 = (long)blockIdx.x * 64;   // blocks 0..1023 fake, 1024..2047 real
    const float* X = (grow0 < 65536) ? (Xf + (size_t)grow0 * 512)
                                     : (Xr + (size_t)(grow0 - 65536) * 512);

    // ======== Layer 1: X[64x512] @ W1 -> h1[64x1024], X staged in 4 K-chunks ========
    f32x16 acc1[4][2];
#pragma unroll
    for (int c = 0; c < 4; ++c)
#pragma unroll
        for (int rt = 0; rt < 2; ++rt)
#pragma unroll
            for (int rg = 0; rg < 16; ++rg) acc1[c][rt][rg] = 0.f;

    // staging map: idx = it*512 + tidx; row = idx>>5 (32 float4/row), cf4 = idx&31
    float4 xr[4];
#pragma unroll
    for (int it = 0; it < 4; ++it) {
        int idx = it * 512 + tidx; int r = idx >> 5; int c4 = idx & 31;
        xr[it] = *(const float4*)(X + (size_t)r * 512 + c4 * 4);
    }

    for (int ch = 0; ch < 4; ++ch) {
        __syncthreads();   // prior chunk's A-frag reads done before overwrite
#pragma unroll
        for (int it = 0; it < 4; ++it) {
            int idx = it * 512 + tidx; int r = idx >> 5; int c4 = idx & 31;
            short4v s;
            s[0] = (short)f2bf(xr[it].x); s[1] = (short)f2bf(xr[it].y);
            s[2] = (short)f2bf(xr[it].z); s[3] = (short)f2bf(xr[it].w);
            *(short4v*)(smem + r * 256 + ((c4 * 8) ^ ((r & 15) << 4))) = s;
        }
        __syncthreads();
        if (ch < 3) {   // prefetch next chunk into regs; HBM latency hides under MFMAs
#pragma unroll
            for (int it = 0; it < 4; ++it) {
                int idx = it * 512 + tidx; int r = idx >> 5; int c4 = idx & 31;
                xr[it] = *(const float4*)(X + (size_t)r * 512 + (ch + 1) * 128 + c4 * 4);
            }
        }
#pragma unroll
        for (int kl = 0; kl < 8; ++kl) {
            int kk = ch * 8 + kl;
            short8 a[2];
#pragma unroll
            for (int rt = 0; rt < 2; ++rt) {
                int row = rt * 32 + l31;
                int kb  = (kl * 16 + hi * 8) * 2;
                a[rt] = *(const short8*)(smem + row * 256 + (kb ^ ((row & 15) << 4)));
            }
#pragma unroll
            for (int c = 0; c < 4; ++c) {
                int ct = wid * 4 + c;
                short8 b = *(const short8*)(pW1 + (((size_t)ct * 32 + kk) * 64 + lane) * 8);
                acc1[c][0] = MFMA32(a[0], b, acc1[c][0], 0, 0, 0);
                acc1[c][1] = MFMA32(a[1], b, acc1[c][1], 0, 0, 0);
            }
        }
    }
    // epilogue L1 -> h1 (rowBytes 2048). C/D map: col=lane&31, row=(rg&3)+8*(rg>>2)+4*hi
#pragma unroll
    for (int c = 0; c < 4; ++c) {
        int ct = wid * 4 + c; int col = ct * 32 + l31;
        float bias = (col < 1000) ? b1[col] : 0.f;
#pragma unroll
        for (int rt = 0; rt < 2; ++rt)
#pragma unroll
            for (int rg = 0; rg < 16; ++rg) {
                int row = rt * 32 + (rg & 3) + 8 * (rg >> 2) + 4 * hi;
                float v = fmaxf(acc1[c][rt][rg] + bias, 0.f);
                *(unsigned short*)(H + row * 2048 + ((col * 2) ^ ((row & 15) << 4))) = f2bf(v);
            }
    }
    __syncthreads();

    // ======== Layer 2: h1[64x1024] @ W2 -> h2[64x512] (acc in regs, then overwrite) ========
    f32x16 acc2[2][2];
#pragma unroll
    for (int c = 0; c < 2; ++c)
#pragma unroll
        for (int rt = 0; rt < 2; ++rt)
#pragma unroll
            for (int rg = 0; rg < 16; ++rg) acc2[c][rt][rg] = 0.f;

#pragma unroll 4
    for (int kk = 0; kk < 64; ++kk) {
        short8 a[2];
#pragma unroll
        for (int rt = 0; rt < 2; ++rt) {
            int row = rt * 32 + l31;
            int kb  = (kk * 16 + hi * 8) * 2;
            a[rt] = *(const short8*)(H + row * 2048 + (kb ^ ((row & 15) << 4)));
        }
#pragma unroll
        for (int c = 0; c < 2; ++c) {
            int ct = wid * 2 + c;
            short8 b = *(const short8*)(pW2 + (((size_t)ct * 64 + kk) * 64 + lane) * 8);
            acc2[c][0] = MFMA32(a[0], b, acc2[c][0], 0, 0, 0);
            acc2[c][1] = MFMA32(a[1], b, acc2[c][1], 0, 0, 0);
        }
    }
    __syncthreads();   // all h1 reads complete before overwriting region
#pragma unroll
    for (int c = 0; c < 2; ++c) {
        int ct = wid * 2 + c; int col = ct * 32 + l31;
        float bias = (col < 500) ? b2[col] : 0.f;
#pragma unroll
        for (int rt = 0; rt < 2; ++rt)
#pragma unroll
            for (int rg = 0; rg < 16; ++rg) {
                int row = rt * 32 + (rg & 3) + 8 * (rg >> 2) + 4 * hi;
                float v = fmaxf(acc2[c][rt][rg] + bias, 0.f);
                *(unsigned short*)(H + row * 1024 + ((col * 2) ^ ((row & 15) << 4))) = f2bf(v);
            }
    }
    __syncthreads();

    // ======== Layer 3: h2[64x512] @ W3 -> h3[64x256] at H+65536 ========
    f32x16 acc3[2];
#pragma unroll
    for (int rt = 0; rt < 2; ++rt)
#pragma unroll
        for (int rg = 0; rg < 16; ++rg) acc3[rt][rg] = 0.f;

#pragma unroll 4
    for (int kk = 0; kk < 32; ++kk) {
        short8 a[2];
#pragma unroll
        for (int rt = 0; rt < 2; ++rt) {
            int row = rt * 32 + l31;
            int kb  = (kk * 16 + hi * 8) * 2;
            a[rt] = *(const short8*)(H + row * 1024 + (kb ^ ((row & 15) << 4)));
        }
        short8 b = *(const short8*)(pW3 + (((size_t)wid * 32 + kk) * 64 + lane) * 8);
        acc3[0] = MFMA32(a[0], b, acc3[0], 0, 0, 0);
        acc3[1] = MFMA32(a[1], b, acc3[1], 0, 0, 0);
    }
    __syncthreads();
    {
        int col = wid * 32 + l31;
        float bias = (col < 250) ? b3[col] : 0.f;
#pragma unroll
        for (int rt = 0; rt < 2; ++rt)
#pragma unroll
            for (int rg = 0; rg < 16; ++rg) {
                int row = rt * 32 + (rg & 3) + 8 * (rg >> 2) + 4 * hi;
                float v = fmaxf(acc3[rt][rg] + bias, 0.f);
                *(unsigned short*)(H + 65536 + row * 512 + ((col * 2) ^ ((row & 15) << 4))) = f2bf(v);
            }
    }
    __syncthreads();

    // ======== Layer 4 + loss: z = h3 . W4 + b4, 8 threads per row ========
    {
        int g  = tidx >> 3;      // row 0..63
        int t8 = tidx & 7;
        float sum = 0.f;
#pragma unroll
        for (int q = 0; q < 4; ++q) {
            int colb = t8 * 32 + q * 8;
            short8 v = *(const short8*)(H + 65536 + g * 512 + ((colb * 2) ^ ((g & 15) << 4)));
#pragma unroll
            for (int j = 0; j < 8; ++j) {
                int cc = colb + j;
                sum += (cc < 250) ? bf2f((unsigned short)v[j]) * W4[cc] : 0.f;
            }
        }
        sum += __shfl_down(sum, 4, 8);
        sum += __shfl_down(sum, 2, 8);
        sum += __shfl_down(sum, 1, 8);
        if (t8 == 0) {
            float z = sum + b4[0];
            bool fake = (grow0 < 65536);
            float spn = softplus(-z);
            red[g]      = fake ? spn : 0.f;               // loss_F part
            red[64 + g] = fake ? softplus(z) : spn;       // loss_D part
        }
    }
    __syncthreads();
    if (tidx == 0) {
        float pF = 0.f, pD = 0.f;
        for (int i = 0; i < 64; ++i) { pF += red[i]; pD += red[64 + i]; }
        partials[(size_t)blockIdx.x * 2]     = pF;
        partials[(size_t)blockIdx.x * 2 + 1] = pD;
    }
}

// ---------------- final reduction ----------------
__global__ void reduce_partials(const float* __restrict__ partials, int nblocks,
                                float* __restrict__ out) {
    __shared__ float sF[256], sD[256];
    float f = 0.f, d = 0.f;
    for (int i = threadIdx.x; i < nblocks; i += 256) {
        f += partials[2 * i];
        d += partials[2 * i + 1];
    }
    sF[threadIdx.x] = f; sD[threadIdx.x] = d;
    __syncthreads();
    for (int s = 128; s > 0; s >>= 1) {
        if (threadIdx.x < s) {
            sF[threadIdx.x] += sF[threadIdx.x + s];
            sD[threadIdx.x] += sD[threadIdx.x + s];
        }
        __syncthreads();
    }
    if (threadIdx.x == 0) { out[0] = sF[0]; out[1] = sD[0]; }
}

extern "C" void kernel_launch(void* const* d_in, const int* in_sizes, int n_in,
                              void* d_out, int out_size, void* d_ws, size_t ws_size,
                              hipStream_t stream) {
    const float* Xf = (const float*)d_in[0];   // repr_xy_hat [65536,512]
    const float* Xr = (const float*)d_in[1];   // repr_xy     [65536,512]
    const float* W1 = (const float*)d_in[2];   // [512,1000]
    const float* b1 = (const float*)d_in[3];
    const float* W2 = (const float*)d_in[4];   // [1000,500]
    const float* b2 = (const float*)d_in[5];
    const float* W3 = (const float*)d_in[6];   // [500,250]
    const float* b3 = (const float*)d_in[7];
    const float* W4 = (const float*)d_in[8];   // [250,1]
    const float* b4 = (const float*)d_in[9];

    // ws layout:
    unsigned short* pW1 = (unsigned short*)d_ws;      // CT32*KT32*64*8 = 524288 (1 MB)
    unsigned short* pW2 = pW1 + 524288;               // CT16*KT64*64*8 = 524288 (1 MB)
    unsigned short* pW3 = pW2 + 524288;               // CT8 *KT32*64*8 = 131072 (256 KB)
    float* partials = (float*)(pW3 + 131072);         // 2048*2 floats (16 KB)

    pack_w32<<<(32 * 32 * 64) / 256, 256, 0, stream>>>(W1, pW1, 512, 1000, 32, 32);
    pack_w32<<<(16 * 64 * 64) / 256, 256, 0, stream>>>(W2, pW2, 1000, 500, 64, 16);
    pack_w32<<<(8 * 32 * 64) / 256, 256, 0, stream>>>(W3, pW3, 500, 250, 32, 8);

    fused_mlp<<<2048, 512, 0, stream>>>(Xf, Xr, pW1, pW2, pW3,
                                        b1, b2, b3, W4, b4, partials);

    reduce_partials<<<1, 256, 0, stream>>>(partials, 2048, (float*)d_out);
}